// Round 9
// baseline (186.232 us; speedup 1.0000x reference)
//
#include <hip/hip_runtime.h>

// Problem constants
#define NTOK 65536          // B*S tokens
#define DDIM 64             // embedding dim
#define KCB  4096           // codebook size
#define MB   64             // tokens per block
#define NTILES 256          // 16-col tiles in codebook
#define TPW  128            // tiles per wave (half codebook; 2 waves share a half)
#define LCAP 4096           // candidate capacity (~1300/block; exhaustive fallback on overflow)
#define WWIN 5.0e-4f        // >= 2*delta; delta <= 2.2e-4 (single-product worst case)
#define IDXOFF  (NTOK * DDIM)
#define LOSSOFF (NTOK * DDIM + NTOK)
#define ZPAD 68             // LDS row stride (floats): 272B, 16B-aligned, breaks banks

typedef __bf16 bf16x8 __attribute__((ext_vector_type(8)));
typedef float  f32x4  __attribute__((ext_vector_type(4)));

__device__ __forceinline__ float opaque(float x) { asm volatile("" : "+v"(x)); return x; }

// numpy pairwise sum of squares, n=64
__device__ __forceinline__ float np_sumsq64(const float* __restrict__ v) {
    float r[8];
#pragma unroll
    for (int j = 0; j < 8; ++j) r[j] = opaque(v[j] * v[j]);
#pragma unroll
    for (int i = 1; i < 8; ++i)
#pragma unroll
        for (int j = 0; j < 8; ++j) r[j] += opaque(v[8 * i + j] * v[8 * i + j]);
    return ((r[0] + r[1]) + (r[2] + r[3])) + ((r[4] + r[5]) + (r[6] + r[7]));
}

__device__ __forceinline__ unsigned short bf16rne(float x) {
    unsigned u = __float_as_uint(x);
    return (unsigned short)((u + 0x7fffu + ((u >> 16) & 1u)) >> 16);
}

// ---- Prep: exact e2 (np pairwise) + fragment-packed bf16(high) codebook ----
// pfh[tile*128 + kh*64 + lane]: lane = quad*16+l15 holds
//   bf16(e_row[tile*16+l15][quad*8 + kh*32 .. +8])  (16 B = 8 bf16)
__global__ void k_prep(const float* __restrict__ emb, float* __restrict__ e2,
                       uint4* __restrict__ pfh, double* __restrict__ lossacc) {
    int k = blockIdx.x * blockDim.x + threadIdx.x;
    if (k == 0) *lossacc = 0.0;
    if (k >= KCB) return;
    float row[DDIM];
    const float4* r4 = (const float4*)(emb + (size_t)k * DDIM);
#pragma unroll
    for (int i = 0; i < DDIM / 4; ++i) {
        float4 v = r4[i];
        row[4*i+0] = v.x; row[4*i+1] = v.y; row[4*i+2] = v.z; row[4*i+3] = v.w;
    }
    e2[k] = np_sumsq64(row);
    const int tile = k >> 4, rr = k & 15;
#pragma unroll
    for (int q = 0; q < 4; ++q) {
#pragma unroll
        for (int kh = 0; kh < 2; ++kh) {
            union { uint4 v; unsigned short s[8]; } th;
#pragma unroll
            for (int j = 0; j < 8; ++j) th.s[j] = bf16rne(row[q*8 + kh*32 + j]);
            pfh[(size_t)tile * 128 + kh * 64 + q * 16 + rr] = th.v;
        }
    }
}

// ---- Main: fixed-thr MFMA sweep, ballot capture, scalar-batched append ----
// Shape (proven r0-r8): 256 thr / 4 waves; wave (g,hh) owns 32 tokens x half
// codebook; VGPR<=64 -> 4 waves/SIMD; LDS 35.1KB -> 4 blocks/CU.
// R8 was VALU-bloated (~190 instr/pair vs ~35 needed): (1) cndmask/or mask
// build 3 ops/h -> now 16 __ballot (1 v_cmp->SGPR each; SAME predicate
// a[r]<=thr[i], bit-identical candidate set); (2) per-candidate LDS atomicAdd
// (latency-serial, same-address contention) -> ONE atomicAdd(tot)/pair by
// lane 0 + independent ds_writes, (m,ncol) decoded from ballot bit index in
// SALU (bit b = hitting lane = (quad=b>>4, l15=b&15)); (3) prefetch rotation
// movs under unroll 1 -> always-prefetch main loop + peeled tail + unroll 2
// so renaming kills the copies. thr FIXED after 512-code preview seed
// (superset guarantee, r5/r7/r8-proven). LCAP overflow -> exhaustive fallback.
// Exact rescore from LDS z: s = fl(fl(z2+e2)-seqFMA(2z*e)) -> lex (s,n).
__global__ __launch_bounds__(256, 4)
void k_vq(const float* __restrict__ z, const float* __restrict__ emb,
          const float* __restrict__ e2g, const uint4* __restrict__ pfh,
          float* __restrict__ out, double* __restrict__ lossacc) {
    __shared__ float z2s[MB];
    __shared__ unsigned v0u[MB];
    __shared__ unsigned long long keys[MB];
    __shared__ unsigned list[LCAP];          // 16 KB; reused as red[] after rescore
    __shared__ int lcnt;
    __shared__ int bidx_s[MB];
    __shared__ float zrow_s[MB][ZPAD];       // 17 KB staged z block

    const int tid  = threadIdx.x;
    const int lane = tid & 63;
    const int l15  = lane & 15;
    const int quad = lane >> 4;
    const int wn   = tid >> 6;
    const int g    = wn >> 1;    // token half: tokens [g*32, g*32+32)
    const int hh   = wn & 1;     // tile half: tiles [hh*128, hh*128+128)
    const int tok0 = blockIdx.x * MB;
    const size_t zbase = (size_t)tok0 * DDIM;

    if (tid < MB) { v0u[tid] = 0x7f800000u; keys[tid] = 0xFFFFFFFFFFFFFFFFull; }
    if (tid == 0) lcnt = 0;

    // ---- A-fragments: bf16(-2z) for this wave's 32 tokens — 16 VGPRs ----
    bf16x8 Ah[2][2];   // [ms_local][kh]
#pragma unroll
    for (int ms = 0; ms < 2; ++ms) {
        const float* p = z + zbase + (size_t)((2 * g + ms) * 16 + l15) * DDIM + quad * 8;
#pragma unroll
        for (int kh = 0; kh < 2; ++kh) {
            float4 u0 = *(const float4*)(p + kh * 32);
            float4 u1 = *(const float4*)(p + kh * 32 + 4);
            float d[8] = {-(u0.x + u0.x), -(u0.y + u0.y), -(u0.z + u0.z), -(u0.w + u0.w),
                          -(u1.x + u1.x), -(u1.y + u1.y), -(u1.z + u1.z), -(u1.w + u1.w)};
            union { bf16x8 v; unsigned short u[8]; } th;
#pragma unroll
            for (int j = 0; j < 8; ++j) th.u[j] = bf16rne(d[j]);
            Ah[ms][kh] = th.v;
        }
    }

    // ---- Stage z block -> LDS (coalesced float4; rows padded to 68) ----
#pragma unroll
    for (int it = 0; it < 4; ++it) {
        int f = it * 256 + tid;              // 0..1023 float4 slots
        int tt = f >> 4, cc = f & 15;
        float4 v = ((const float4*)(z + zbase))[f];
        *(float4*)&zrow_s[tt][cc * 4] = v;
    }
    __syncthreads();   // zrow_s ready (also covers v0u/keys/lcnt init)

    // z2 per token (exact np pairwise) from LDS
    if (tid < MB) {
        float row[DDIM];
#pragma unroll
        for (int i = 0; i < DDIM / 4; ++i) {
            float4 v = *(const float4*)&zrow_s[tid][i * 4];
            row[4*i+0] = v.x; row[4*i+1] = v.y; row[4*i+2] = v.z; row[4*i+3] = v.w;
        }
        z2s[tid] = np_sumsq64(row);
    }

    const uint4* pbase = pfh + (size_t)hh * 128 * 128 + lane;

    // ---- preview (16 tiles/wave; 2 waves/token-half -> 512-code seed) ----
    float rm[8];
#pragma unroll
    for (int i = 0; i < 8; ++i) rm[i] = 3.0e38f;
#pragma unroll 1
    for (int t = 0; t < 16; ++t) {
        union { uint4 q; bf16x8 v; } b0, b1;
        b0.q = pbase[(size_t)t * 128]; b1.q = pbase[(size_t)t * 128 + 64];
#pragma unroll
        for (int ms = 0; ms < 2; ++ms) {
            f32x4 a = {0.5f, 0.5f, 0.5f, 0.5f};
            a = __builtin_amdgcn_mfma_f32_16x16x32_bf16(Ah[ms][0], b0.v, a, 0, 0, 0);
            a = __builtin_amdgcn_mfma_f32_16x16x32_bf16(Ah[ms][1], b1.v, a, 0, 0, 0);
#pragma unroll
            for (int r = 0; r < 4; ++r) rm[ms*4+r] = fminf(rm[ms*4+r], a[r]);
        }
    }
    // commit raw mins (16-lane group reduce -> block atomicMin)
#pragma unroll
    for (int i = 0; i < 8; ++i) {
        float v = rm[i];
        v = fminf(v, __shfl_xor(v, 1));
        v = fminf(v, __shfl_xor(v, 2));
        v = fminf(v, __shfl_xor(v, 4));
        v = fminf(v, __shfl_xor(v, 8));
        if (l15 == 0)
            atomicMin(&v0u[(2*g + (i>>2)) * 16 + quad*4 + (i&3)], __float_as_uint(v));
    }
    __syncthreads();   // v0u complete block-wide

    float thr[8];      // FIXED for the whole sweep: block 512-code min + W
#pragma unroll
    for (int i = 0; i < 8; ++i)
        thr[i] = __uint_as_float(v0u[(2*g + (i>>2)) * 16 + quad*4 + (i&3)]) + WWIN;

    // ---- main sweep: 2 tiles/pair, ballot capture, scalar batched append ----
    auto sweep_pair = [&](uint4 p0, uint4 p1, uint4 q0, uint4 q1, int t) {
        f32x4 acc[4];   // [ts*2+ms], constant-indexed throughout
        {
            union { uint4 q; bf16x8 v; } b0u, b1u;
            b0u.q = p0; b1u.q = p1;
#pragma unroll
            for (int ms = 0; ms < 2; ++ms) {
                f32x4 a = {0.5f, 0.5f, 0.5f, 0.5f};
                a = __builtin_amdgcn_mfma_f32_16x16x32_bf16(Ah[ms][0], b0u.v, a, 0, 0, 0);
                a = __builtin_amdgcn_mfma_f32_16x16x32_bf16(Ah[ms][1], b1u.v, a, 0, 0, 0);
                acc[ms] = a;
            }
        }
        {
            union { uint4 q; bf16x8 v; } b0u, b1u;
            b0u.q = q0; b1u.q = q1;
#pragma unroll
            for (int ms = 0; ms < 2; ++ms) {
                f32x4 a = {0.5f, 0.5f, 0.5f, 0.5f};
                a = __builtin_amdgcn_mfma_f32_16x16x32_bf16(Ah[ms][0], b0u.v, a, 0, 0, 0);
                a = __builtin_amdgcn_mfma_f32_16x16x32_bf16(Ah[ms][1], b1u.v, a, 0, 0, 0);
                acc[2 + ms] = a;
            }
        }
        // 16 ballots: 1 v_cmp->SGPR each; predicate identical to R8
        unsigned long long hit[16];
#pragma unroll
        for (int k = 0; k < 16; ++k) {
            const int ts = k >> 3, ms = (k >> 2) & 1, r = k & 3;
            hit[k] = __ballot(acc[ts * 2 + ms][r] <= thr[ms * 4 + r]);
        }
        int tot = 0;
#pragma unroll
        for (int k = 0; k < 16; ++k) tot += __popcll(hit[k]);
        if (tot) {                    // wave-uniform; taken ~99% (lambda ~5)
            if (lane == 0) {          // single-lane batched append
                int base = atomicAdd(&lcnt, tot);
                int j = 0;
#pragma unroll
                for (int k = 0; k < 16; ++k) {
                    unsigned long long hm = hit[k];
                    const int ts = k >> 3, ms = (k >> 2) & 1, r = k & 3;
                    while (hm) {      // scalar loop; bit b = hitting lane id
                        int b = (int)__builtin_ctzll(hm);
                        hm &= hm - 1;
                        int m    = (2 * g + ms) * 16 + (b >> 4) * 4 + r;
                        int ncol = hh * 2048 + (t + ts) * 16 + (b & 15);
                        int idx = base + j; ++j;
                        if (idx < LCAP)
                            list[idx] = ((unsigned)m << 12) | (unsigned)ncol;
                    }
                }
            }
        }
    };

    uint4 a0 = pbase[0],   a1 = pbase[64];
    uint4 b0 = pbase[128], b1 = pbase[192];
#pragma unroll 2
    for (int t = 0; t < TPW - 2; t += 2) {   // always-prefetch main loop
        uint4 c0 = pbase[(size_t)(t + 2) * 128];
        uint4 c1 = pbase[(size_t)(t + 2) * 128 + 64];
        uint4 d0 = pbase[(size_t)(t + 3) * 128];
        uint4 d1 = pbase[(size_t)(t + 3) * 128 + 64];
        sweep_pair(a0, a1, b0, b1, t);
        a0 = c0; a1 = c1; b0 = d0; b1 = d1;
    }
    sweep_pair(a0, a1, b0, b1, TPW - 2);     // peeled tail (no prefetch)
    __syncthreads();   // list complete & visible

    // ---- Exact rescore (np chain), lexicographic (s, n) min per token ----
    int cnt = lcnt;
    if (cnt <= LCAP) {
        for (int i = tid; i < cnt; i += 256) {
            unsigned e = list[i];
            int m = (int)(e >> 12), n = (int)(e & 4095u);
            const float4* er4 = (const float4*)(emb + (size_t)n * DDIM);
            const float4* zr4 = (const float4*)&zrow_s[m][0];
            float a = 0.f;
#pragma unroll
            for (int j4 = 0; j4 < 16; ++j4) {
                float4 ev = er4[j4];
                float4 zv = zr4[j4];
                a = fmaf(zv.x + zv.x, ev.x, a);
                a = fmaf(zv.y + zv.y, ev.y, a);
                a = fmaf(zv.z + zv.z, ev.z, a);
                a = fmaf(zv.w + zv.w, ev.w, a);
            }
            float s = (z2s[m] + e2g[n]) - a;   // two fp32 roundings, exactly as np
            unsigned long long key = ((unsigned long long)__float_as_uint(s) << 32)
                                   | (unsigned long long)(unsigned)n;
            atomicMin(&keys[m], key);
        }
    } else {
        // overflow fallback: exhaustive exact rescore (correctness insurance)
        for (int i = tid; i < MB * KCB; i += 256) {
            int m = i >> 12, n = i & 4095;
            const float4* er4 = (const float4*)(emb + (size_t)n * DDIM);
            const float4* zr4 = (const float4*)&zrow_s[m][0];
            float a = 0.f;
#pragma unroll
            for (int j4 = 0; j4 < 16; ++j4) {
                float4 ev = er4[j4];
                float4 zv = zr4[j4];
                a = fmaf(zv.x + zv.x, ev.x, a);
                a = fmaf(zv.y + zv.y, ev.y, a);
                a = fmaf(zv.z + zv.z, ev.z, a);
                a = fmaf(zv.w + zv.w, ev.w, a);
            }
            float s = (z2s[m] + e2g[n]) - a;
            unsigned long long key = ((unsigned long long)__float_as_uint(s) << 32)
                                   | (unsigned long long)(unsigned)n;
            atomicMin(&keys[m], key);
        }
    }
    __syncthreads();

    if (tid < MB) {
        int nstar = (int)(keys[tid] & 0xffffffffULL);
        bidx_s[tid] = nstar;
        out[IDXOFF + tok0 + tid] = (float)nstar;
    }
    __syncthreads();

    // ---- Epilogue: quantized gather-write (coalesced float4) + loss ----
    float* red = (float*)list;    // list is dead past the rescore barrier
    float lsum = 0.f;
#pragma unroll
    for (int it = 0; it < 4; ++it) {
        int f  = it * 256 + tid;    // 0..1023 float4 slots (64 tok * 16)
        int tt = f >> 4, cc = f & 15;
        int idx = bidx_s[tt];
        float4 qv = ((const float4*)(emb + (size_t)idx * DDIM))[cc];
        float4 zv = *(const float4*)&zrow_s[tt][cc * 4];
        ((float4*)(out + zbase))[f] = qv;
        float dx = qv.x - zv.x, dy = qv.y - zv.y;
        float dz = qv.z - zv.z, dw = qv.w - zv.w;
        lsum += dx * dx + dy * dy + dz * dz + dw * dw;
    }
    red[tid] = lsum;
    __syncthreads();
    for (int s = 128; s > 0; s >>= 1) {
        if (tid < s) red[tid] += red[tid + s];
        __syncthreads();
    }
    if (tid == 0) atomicAdd(lossacc, (double)red[0]);
}

__global__ void k_fin(const double* __restrict__ lossacc, float* __restrict__ out) {
    out[LOSSOFF] = (float)(2.0 * (*lossacc) / (double)(NTOK * DDIM));
}

extern "C" void kernel_launch(void* const* d_in, const int* in_sizes, int n_in,
                              void* d_out, int out_size, void* d_ws, size_t ws_size,
                              hipStream_t stream) {
    const float* z   = (const float*)d_in[0];   // [16,4096,64] fp32
    const float* emb = (const float*)d_in[1];   // [4096,64] fp32
    float* out = (float*)d_out;

    char* ws = (char*)d_ws;
    float*  e2g     = (float*)(ws);                 // 16 KB
    uint4*  pfh     = (uint4*)(ws + 16384);         // 512 KB packed high frags
    double* lossacc = (double*)(ws + 16384 + 524288);

    hipLaunchKernelGGL(k_prep, dim3(64), dim3(64), 0, stream, emb, e2g, pfh, lossacc);
    hipLaunchKernelGGL(k_vq, dim3(NTOK / MB), dim3(256), 0, stream,
                       z, emb, e2g, pfh, out, lossacc);
    hipLaunchKernelGGL(k_fin, dim3(1), dim3(1), 0, stream, lossacc, out);
}